// Round 2
// baseline (561.437 us; speedup 1.0000x reference)
//
#include <hip/hip_runtime.h>
#include <stdint.h>

#define FEAT 128
#define NNODES 512
#define BATCH 4
#define EDGES 97920              // sum_{r=257}^{511} r
#define BE (BATCH*EDGES)         // 391680
#define NSAMP 5
#define BASE_OFF 32896           // 256*257/2
#define CHUNKS 40                // gumbel blocks per (b,s)

// ---------------- threefry2x32 (exact JAX core, key=[0,42]) ------------------
__device__ __forceinline__ void threefry2x32(uint32_t k0, uint32_t k1,
                                             uint32_t& x0, uint32_t& x1) {
  uint32_t k2 = k0 ^ k1 ^ 0x1BD11BDAu;
  x0 += k0; x1 += k1;
#define RR(r) { x0 += x1; x1 = (x1 << (r)) | (x1 >> (32 - (r))); x1 ^= x0; }
  RR(13) RR(15) RR(26) RR(6)   x0 += k1; x1 += k2 + 1u;
  RR(17) RR(29) RR(16) RR(24)  x0 += k2; x1 += k0 + 2u;
  RR(13) RR(15) RR(26) RR(6)   x0 += k0; x1 += k1 + 3u;
  RR(17) RR(29) RR(16) RR(24)  x0 += k1; x1 += k2 + 4u;
  RR(13) RR(15) RR(26) RR(6)   x0 += k2; x1 += k0 + 5u;
#undef RR
}

// Gumbel noise for flat index n into (B, NSAMP, E), matching jax.random.gumbel
// with jax_threefry_partitionable=True (modern default): per-element 64-bit
// counter n -> (x0=hi32=0, x1=lo32=n), 32-bit bits = xor-fold of the two
// output words. Then u = max(tiny, bitcast(bits>>9 | 0x3f800000) - 1),
// g = -log(-log(u)).
// RNG_VARIANT: 0 = xor-fold (this round), 1 = word0 only, 2 = word1 only.
#define RNG_VARIANT 0
__device__ __forceinline__ double gumbel_val(uint32_t n) {
  uint32_t x0 = 0u, x1 = n;      // (counter >> 32, counter & 0xffffffff)
  threefry2x32(0u, 42u, x0, x1);
#if RNG_VARIANT == 0
  uint32_t bits = x0 ^ x1;
#elif RNG_VARIANT == 1
  uint32_t bits = x0;
#else
  uint32_t bits = x1;
#endif
  uint32_t fb = (bits >> 9) | 0x3f800000u;
  float f = __uint_as_float(fb) - 1.0f;
  float u = fmaxf(f, 1.1754943508222875e-38f);
  return -log(-log((double)u));
}

__device__ __forceinline__ float wave_sum(float v) {
#pragma unroll
  for (int off = 32; off; off >>= 1) v += __shfl_xor(v, off, 64);
  return v;
}

// ---------------- kernel A: P = nodes @ W1_top, Q = nodes @ W1_bot -----------
__global__ __launch_bounds__(256) void pq_kernel(
    const float* __restrict__ nodes, const float* __restrict__ W1,
    float* __restrict__ P, float* __restrict__ Q) {
  __shared__ float snode[8][FEAT];
  const int row0 = blockIdx.x * 8;            // (b*512+n) rows, 8 per block
  const int tid = threadIdx.x;
  for (int i = tid; i < 8 * FEAT; i += 256)
    snode[i >> 7][i & 127] = nodes[row0 * FEAT + i];
  __syncthreads();
  const int j = tid & 127;
  const int half = tid >> 7;                   // 0 -> P, 1 -> Q
  const float* w = W1 + half * FEAT * FEAT + j;
  float acc[8] = {0, 0, 0, 0, 0, 0, 0, 0};
  for (int k = 0; k < FEAT; ++k) {
    float wv = w[k * FEAT];
#pragma unroll
    for (int m = 0; m < 8; ++m) acc[m] += snode[m][k] * wv;
  }
  float* out = half ? Q : P;
#pragma unroll
  for (int m = 0; m < 8; ++m) out[(row0 + m) * FEAT + j] = acc[m];
}

// ---------------- edge index -> (sink, src) ----------------------------------
__global__ __launch_bounds__(256) void map_kernel(int2* __restrict__ map) {
  int e = blockIdx.x * blockDim.x + threadIdx.x;
  if (e >= EDGES) return;
  double x = (double)(e + BASE_OFF);
  int s = (int)((1.0 + sqrt(1.0 + 8.0 * x)) * 0.5);
  while ((long long)s * (s - 1) / 2 - BASE_OFF > e) --s;
  while ((long long)(s + 1) * s / 2 - BASE_OFF <= e) ++s;
  int src = e - (int)((long long)s * (s - 1) / 2 - BASE_OFF);
  map[e] = make_int2(s, src);
}

// ---------------- main MLP kernel: logits[b*E+e] -----------------------------
__global__ __launch_bounds__(256) void mlp_kernel(
    const float* __restrict__ P, const float* __restrict__ Q,
    const int2* __restrict__ map, const float* __restrict__ W2,
    const float* __restrict__ b1, const float* __restrict__ g1,
    const float* __restrict__ be1, const float* __restrict__ b2,
    const float* __restrict__ g2, const float* __restrict__ be2,
    const float* __restrict__ W3, const float* __restrict__ b3,
    float* __restrict__ logits) {
  __shared__ float sW2[64 * FEAT];   // one k-half of W2, 32 KB
  __shared__ float sx[4][8][132];    // per-wave x tiles, 16.9 KB
  const int tid = threadIdx.x;
  const int lane = tid & 63;
  const int wave = tid >> 6;
  const int l2 = lane * 2;

  const float b1a = b1[l2], b1b = b1[l2 + 1];
  const float g1a = g1[l2], g1b = g1[l2 + 1];
  const float e1a = be1[l2], e1b = be1[l2 + 1];
  const float b2a = b2[l2], b2b = b2[l2 + 1];
  const float g2a = g2[l2], g2b = g2[l2 + 1];
  const float e2a = be2[l2], e2b = be2[l2 + 1];
  const float w3a = W3[l2], w3b = W3[l2 + 1];
  const float bias3 = b3[0];

  const int ntiles = BE / 32;  // 12240, exact
  for (int tile = blockIdx.x; tile < ntiles; tile += gridDim.x) {
    const int g0 = tile * 32 + wave * 8;

    // ---- stage 1: h1 = LN(relu(P[sink]+Q[src]+b1)) for 8 edges ----
    float xa[8], xb[8];
#pragma unroll
    for (int m = 0; m < 8; ++m) {
      int g = g0 + m;
      int b = g / EDGES;
      int e = g - b * EDGES;
      int2 ss = map[e];
      const float* prow = P + (((b << 9) + ss.x) << 7);
      const float* qrow = Q + (((b << 9) + ss.y) << 7);
      float2 pv = *(const float2*)(prow + l2);
      float2 qv = *(const float2*)(qrow + l2);
      float h0 = fmaxf(pv.x + qv.x + b1a, 0.0f);
      float h1 = fmaxf(pv.y + qv.y + b1b, 0.0f);
      float s = wave_sum(h0 + h1);
      float q = wave_sum(h0 * h0 + h1 * h1);
      float mu = s * (1.0f / 128.0f);
      float var = q * (1.0f / 128.0f) - mu * mu;
      float rstd = 1.0f / sqrtf(var + 1e-5f);
      xa[m] = (h0 - mu) * rstd * g1a + e1a;
      xb[m] = (h1 - mu) * rstd * g1b + e1b;
    }
#pragma unroll
    for (int m = 0; m < 8; ++m)
      *(float2*)&sx[wave][m][l2] = make_float2(xa[m], xb[m]);

    // ---- stage 2: h2 = x @ W2 (+b2), k in two halves of 64 ----
    float acc0[8], acc1[8];
#pragma unroll
    for (int m = 0; m < 8; ++m) { acc0[m] = b2a; acc1[m] = b2b; }

    for (int kh = 0; kh < 2; ++kh) {
      __syncthreads();  // previous users of sW2 done
      for (int i = tid * 4; i < 64 * FEAT; i += 256 * 4)
        *(float4*)&sW2[i] = *(const float4*)&W2[kh * 64 * FEAT + i];
      __syncthreads();
      for (int k = 0; k < 64; k += 4) {
        float4 xv[8];
#pragma unroll
        for (int m = 0; m < 8; ++m)
          xv[m] = *(const float4*)&sx[wave][m][kh * 64 + k];
#pragma unroll
        for (int kk = 0; kk < 4; ++kk) {
          float2 wv = *(const float2*)&sW2[(k + kk) * FEAT + l2];
#pragma unroll
          for (int m = 0; m < 8; ++m) {
            float xs = ((const float*)&xv[m])[kk];
            acc0[m] += xs * wv.x;
            acc1[m] += xs * wv.y;
          }
        }
      }
    }

    // ---- stage 2 LN + W3 dot ----
#pragma unroll
    for (int m = 0; m < 8; ++m) {
      float h0 = fmaxf(acc0[m], 0.0f);
      float h1 = fmaxf(acc1[m], 0.0f);
      float s = wave_sum(h0 + h1);
      float q = wave_sum(h0 * h0 + h1 * h1);
      float mu = s * (1.0f / 128.0f);
      float var = q * (1.0f / 128.0f) - mu * mu;
      float rstd = 1.0f / sqrtf(var + 1e-5f);
      float y0 = (h0 - mu) * rstd * g2a + e2a;
      float y1 = (h1 - mu) * rstd * g2b + e2b;
      float c = wave_sum(y0 * w3a + y1 * w3b);
      if (lane == 0) logits[g0 + m] = c + bias3;
    }
  }
}

// ---------------- gumbel argmax, stage 1: per-(bs,chunk) best ----------------
__global__ __launch_bounds__(256) void gumbel_kernel(
    const float* __restrict__ logits, double* __restrict__ bestval,
    int* __restrict__ bestidx) {
  const int bs = blockIdx.x / CHUNKS;     // b*5 + s
  const int chunk = blockIdx.x % CHUNKS;
  const int b = bs / NSAMP;
  const float* lg = logits + b * EDGES;
  double best = -1e300; int bi = 0x7fffffff;
  for (int e = chunk * 256 + threadIdx.x; e < EDGES; e += CHUNKS * 256) {
    uint32_t n = (uint32_t)(bs * EDGES + e);
    double val = (double)lg[e] + gumbel_val(n);
    if (val > best) { best = val; bi = e; }
  }
  __shared__ double sv[256];
  __shared__ int si[256];
  sv[threadIdx.x] = best; si[threadIdx.x] = bi;
  __syncthreads();
  for (int off = 128; off; off >>= 1) {
    if (threadIdx.x < off) {
      double ov = sv[threadIdx.x + off]; int oi = si[threadIdx.x + off];
      if (ov > sv[threadIdx.x] ||
          (ov == sv[threadIdx.x] && oi < si[threadIdx.x])) {
        sv[threadIdx.x] = ov; si[threadIdx.x] = oi;
      }
    }
    __syncthreads();
  }
  if (threadIdx.x == 0) { bestval[blockIdx.x] = sv[0]; bestidx[blockIdx.x] = si[0]; }
}

// ---------------- gumbel argmax, stage 2: winner -> adj ----------------------
__global__ __launch_bounds__(64) void select_kernel(
    const double* __restrict__ bestval, const int* __restrict__ bestidx,
    const int2* __restrict__ map, float* __restrict__ adj) {
  const int bs = blockIdx.x;
  const int lane = threadIdx.x;
  double v = -1e300; int idx = 0x7fffffff;
  if (lane < CHUNKS) { v = bestval[bs * CHUNKS + lane]; idx = bestidx[bs * CHUNKS + lane]; }
#pragma unroll
  for (int off = 32; off; off >>= 1) {
    double ov = __shfl_xor(v, off, 64);
    int oi = __shfl_xor(idx, off, 64);
    if (ov > v || (ov == v && oi < idx)) { v = ov; idx = oi; }
  }
  if (lane == 0) {
    int b = bs / NSAMP;
    int2 ss = map[idx];
    adj[((b * NNODES) + ss.x) * NNODES + ss.y] = 1.0f;
  }
}

extern "C" void kernel_launch(void* const* d_in, const int* in_sizes, int n_in,
                              void* d_out, int out_size, void* d_ws, size_t ws_size,
                              hipStream_t stream) {
  const float* nodes = (const float*)d_in[0];
  const float* W1  = (const float*)d_in[1];
  const float* b1  = (const float*)d_in[2];
  const float* g1  = (const float*)d_in[3];
  const float* be1 = (const float*)d_in[4];
  const float* W2  = (const float*)d_in[5];
  const float* b2  = (const float*)d_in[6];
  const float* g2  = (const float*)d_in[7];
  const float* be2 = (const float*)d_in[8];
  const float* W3  = (const float*)d_in[9];
  const float* b3  = (const float*)d_in[10];
  float* adj = (float*)d_out;

  char* ws = (char*)d_ws;
  float* P       = (float*)(ws);                 // 1 MB
  float* Q       = (float*)(ws + (1 << 20));     // 1 MB
  int2*  map     = (int2*) (ws + (2 << 20));     // 783 KB
  float* logits  = (float*)(ws + (3 << 20));     // 1.57 MB
  double* bestval = (double*)(ws + (5 << 20));   // 20*40*8
  int*    bestidx = (int*)   (ws + (5 << 20) + 20 * CHUNKS * 8);

  hipMemsetAsync(adj, 0, (size_t)out_size * sizeof(float), stream);
  pq_kernel<<<(BATCH * NNODES) / 8, 256, 0, stream>>>(nodes, W1, P, Q);
  map_kernel<<<(EDGES + 255) / 256, 256, 0, stream>>>(map);
  mlp_kernel<<<2040, 256, 0, stream>>>(P, Q, map, W2, b1, g1, be1,
                                       b2, g2, be2, W3, b3, logits);
  gumbel_kernel<<<20 * CHUNKS, 256, 0, stream>>>(logits, bestval, bestidx);
  select_kernel<<<20, 64, 0, stream>>>(bestval, bestidx, map, adj);
}